// Round 1
// baseline (515.877 us; speedup 1.0000x reference)
//
#include <hip/hip_runtime.h>
#include <math.h>

#define KGT   16
#define NCAND 9
#define NLVL  5
#define NPRI  8525
#define NCLS  80
#define NIMG  32

#define ASSIGN_BLOCKS 32
#define FOCAL_BLOCKS  2016
#define TOTAL_BLOCKS  (ASSIGN_BLOCKS + FOCAL_BLOCKS)

__constant__ int d_SPL[6] = {0, 6400, 8000, 8400, 8500, 8525};

// ws layout: acc[0]=focal_sum (base + corrections), acc[1]=loc_sum, ((int*)acc)[2]=valid count
__global__ __launch_bounds__(256)
void atss_main(const float* __restrict__ locs,
               const float* __restrict__ scores,
               const float* __restrict__ boxes,
               const int*   __restrict__ labels,
               const float* __restrict__ priors,
               float* __restrict__ acc)
{
    const int tid = threadIdx.x;
    const int blk = blockIdx.x;

    __shared__ float wsum[4];

    if (blk >= ASSIGN_BLOCKS) {
        // ---------------- big focal reduction: sum p^2 * softplus(x) over all logits
        const int n4 = (NIMG * NPRI * NCLS) / 4;
        const float4* s4 = (const float4*)scores;
        int gid = (blk - ASSIGN_BLOCKS) * 256 + tid;
        const int stride = FOCAL_BLOCKS * 256;
        float lsum = 0.f;
        for (int i = gid; i < n4; i += stride) {
            float4 v = s4[i];
            #pragma unroll
            for (int c = 0; c < 4; ++c) {
                float x = (c == 0) ? v.x : (c == 1) ? v.y : (c == 2) ? v.z : v.w;
                float e  = __expf(-fabsf(x));            // exp(-|x|)
                float sp = fmaxf(x, 0.f) + __logf(1.f + e); // softplus(x)
                float p  = (x >= 0.f) ? 1.f / (1.f + e) : e / (1.f + e); // sigmoid(x)
                lsum += p * p * sp;
            }
        }
        #pragma unroll
        for (int off = 32; off > 0; off >>= 1) lsum += __shfl_down(lsum, off);
        if ((tid & 63) == 0) wsum[tid >> 6] = lsum;
        __syncthreads();
        if (tid == 0)
            atomicAdd(&acc[0], 0.75f * (wsum[0] + wsum[1] + wsum[2] + wsum[3]));
        return;
    }

    // ---------------- per-image ATSS assignment, image b = blk
    const int b = blk;

    __shared__ float sbox[KGT][4];
    __shared__ float sctr[KGT][2];
    __shared__ int   slab[KGT];
    __shared__ float scr_d[256 * NCAND];
    __shared__ int   scr_i[256 * NCAND];
    __shared__ int   top_i[KGT * NLVL * NCAND];
    __shared__ float pov[KGT * NLVL * NCAND];   // pos_ov, [g][l*9+j]
    __shared__ float thr[KGT];
    __shared__ int   mptr[KGT * 16];

    if (tid < KGT) {
        float4 bx = ((const float4*)boxes)[b * KGT + tid];
        sbox[tid][0] = bx.x; sbox[tid][1] = bx.y;
        sbox[tid][2] = bx.z; sbox[tid][3] = bx.w;
        sctr[tid][0] = (bx.x + bx.z) * 0.5f;
        sctr[tid][1] = (bx.y + bx.w) * 0.5f;
        slab[tid] = labels[b * KGT + tid];
    }
    __syncthreads();

    const int g   = tid >> 4;
    const int sub = tid & 15;
    const float gcx = sctr[g][0], gcy = sctr[g][1];

    const int SPLc[6] = {0, 6400, 8000, 8400, 8500, 8525};

    // Stage B: per (gt,level) top-9 nearest priors (lax.top_k tie semantics)
    #pragma unroll
    for (int l = 0; l < NLVL; ++l) {
        const int base = SPLc[l];
        const int Pl   = SPLc[l + 1] - base;

        float d9[NCAND]; int i9[NCAND];
        #pragma unroll
        for (int s = 0; s < NCAND; ++s) { d9[s] = 3.0e38f; i9[s] = 0x7fffffff; }

        for (int i = sub; i < Pl; i += 16) {
            float2 pc = ((const float2*)priors)[(base + i) * 2];
            float dx = gcx - pc.x, dy = gcy - pc.y;
            float dist = sqrtf(dx * dx + dy * dy);
            if (dist < d9[NCAND - 1]) {       // strict: ties keep earlier index
                d9[NCAND - 1] = dist; i9[NCAND - 1] = i;
                #pragma unroll
                for (int s = NCAND - 1; s >= 1; --s) {
                    if (d9[s] < d9[s - 1]) {  // strict: equal dist -> stay after
                        float td = d9[s]; d9[s] = d9[s - 1]; d9[s - 1] = td;
                        int   ti = i9[s]; i9[s] = i9[s - 1]; i9[s - 1] = ti;
                    } else break;
                }
            }
        }
        #pragma unroll
        for (int s = 0; s < NCAND; ++s) {
            scr_d[tid * NCAND + s] = d9[s];
            scr_i[tid * NCAND + s] = i9[s];
        }
        __syncthreads();

        if (tid < KGT) {  // merge 16 sorted lists for gt=tid: lexicographic (d, idx)
            #pragma unroll
            for (int q = 0; q < 16; ++q) mptr[tid * 16 + q] = 0;
            for (int j = 0; j < NCAND; ++j) {
                float bd = 3.2e38f; int bi = 0x7fffffff; int bl = 0;
                for (int q = 0; q < 16; ++q) {
                    int pp = mptr[tid * 16 + q];
                    float d = scr_d[(tid * 16 + q) * NCAND + pp];
                    int  ii = scr_i[(tid * 16 + q) * NCAND + pp];
                    if (d < bd || (d == bd && ii < bi)) { bd = d; bi = ii; bl = q; }
                }
                mptr[tid * 16 + bl]++;
                top_i[(tid * NLVL + l) * NCAND + j] = bi;
            }
        }
        __syncthreads();
    }

    // Stage C: pos_ov = IoU(box_g, prior_box(top_idx))
    for (int e = tid; e < KGT * NLVL * NCAND; e += 256) {
        int gg = e / (NLVL * NCAND);
        int q  = e % (NLVL * NCAND);
        int l  = q / NCAND;
        int gi = d_SPL[l] + top_i[e];
        float4 pr = ((const float4*)priors)[gi];
        float px0 = pr.x - pr.z * 0.5f, py0 = pr.y - pr.w * 0.5f;
        float px1 = pr.x + pr.z * 0.5f, py1 = pr.y + pr.w * 0.5f;
        float ax0 = sbox[gg][0], ay0 = sbox[gg][1], ax1 = sbox[gg][2], ay1 = sbox[gg][3];
        float iw = fmaxf(fminf(ax1, px1) - fmaxf(ax0, px0), 0.f);
        float ih = fmaxf(fminf(ay1, py1) - fmaxf(ay0, py0), 0.f);
        float inter = iw * ih;
        float areaA = (ax1 - ax0) * (ay1 - ay0);
        float areaP = (px1 - px0) * (py1 - py0);
        pov[e] = inter / (areaA + areaP - inter);
    }
    __syncthreads();

    // Stage D: thr = mean + std(ddof=1) over the 45 candidate IoUs
    if (tid < KGT) {
        float s = 0.f;
        for (int q = 0; q < NLVL * NCAND; ++q) s += pov[tid * 45 + q];
        float mean = s / 45.f;
        float ss = 0.f;
        for (int q = 0; q < NLVL * NCAND; ++q) {
            float d = pov[tid * 45 + q] - mean; ss += d * d;
        }
        thr[tid] = mean + sqrtf(ss / 44.f);
    }
    __syncthreads();

    // Stage E: per (level, cand-column): argmax over GTs, focal correction + CIoU
    if (tid < NLVL * NCAND) {
        int l = tid / NCAND, j = tid % NCAND;
        float bestv = -1.f; int bestg = 0;
        for (int gg = 0; gg < KGT; ++gg) {
            float m = pov[gg * 45 + tid];
            int pi = top_i[(gg * NLVL + l) * NCAND + j];
            float4 pr = ((const float4*)priors)[d_SPL[l] + pi];
            bool inside = (sbox[gg][0] < pr.x) && (pr.x < sbox[gg][2]) &&
                          (sbox[gg][1] < pr.y) && (pr.y < sbox[gg][3]);
            float mm = ((m > thr[gg]) && inside) ? m : 0.f;
            if (mm > bestv) { bestv = mm; bestg = gg; }   // first max wins (argmax)
        }
        if (bestv > 0.f) {
            int lab = slab[bestg];
            // focal correction at prior p = SPL[l]+j, class lab
            int pos = b * NPRI + SPLc[l] + j;
            float x  = scores[(long)pos * NCLS + (lab - 1)];
            float e  = expf(-fabsf(x));
            float l1 = log1pf(e);
            float spp = fmaxf(x, 0.f) + l1;    // softplus(x)
            float spn = fmaxf(-x, 0.f) + l1;   // softplus(-x)
            float p   = (x >= 0.f) ? 1.f / (1.f + e) : e / (1.f + e);
            float corr = 0.25f * (1.f - p) * (1.f - p) * spn - 0.75f * p * p * spp;

            // decode pred box, CIoU vs gt
            int pi = top_i[(bestg * NLVL + l) * NCAND + j];
            float4 pr = ((const float4*)priors)[SPLc[l] + pi];
            float4 lc = ((const float4*)locs)[b * NPRI + SPLc[l] + pi];
            float cx = lc.x * pr.z / 10.f + pr.x;
            float cy = lc.y * pr.w / 10.f + pr.y;
            float w  = expf(lc.z / 5.f) * pr.z;
            float h  = expf(lc.w / 5.f) * pr.w;
            float qx0 = cx - w * 0.5f, qy0 = cy - h * 0.5f;
            float qx1 = cx + w * 0.5f, qy1 = cy + h * 0.5f;
            float gx0 = sbox[bestg][0], gy0 = sbox[bestg][1];
            float gx1 = sbox[bestg][2], gy1 = sbox[bestg][3];
            float w1 = qx1 - qx0, h1 = qy1 - qy0, w2 = gx1 - gx0, h2 = gy1 - gy0;
            float iw = fmaxf(fminf(qx1, gx1) - fmaxf(qx0, gx0), 0.f);
            float ih = fmaxf(fminf(qy1, gy1) - fmaxf(qy0, gy0), 0.f);
            float inter = iw * ih;
            float iou = inter / (w1 * h1 + w2 * h2 - inter);
            float dcx = (qx0 + qx1) * 0.5f - (gx0 + gx1) * 0.5f;
            float dcy = (qy0 + qy1) * 0.5f - (gy0 + gy1) * 0.5f;
            float rho2 = dcx * dcx + dcy * dcy;
            float ex = fmaxf(qx1, gx1) - fminf(qx0, gx0);
            float ey = fmaxf(qy1, gy1) - fminf(qy0, gy0);
            float cdiag = ex * ex + ey * ey;
            float da = atanf(w2 / h2) - atanf(w1 / h1);
            float v  = 0.4052847345693511f * da * da;   // 4/pi^2
            float alpha = v / (1.f - iou + v);
            float ci = iou - rho2 / cdiag - alpha * v;
            ci = fminf(fmaxf(ci, -1.f), 1.f);

            atomicAdd(&acc[0], corr);
            atomicAdd(&acc[1], 1.f - ci);
            atomicAdd((int*)acc + 2, 1);
        }
    }
}

__global__ void atss_finalize(const float* __restrict__ acc, float* __restrict__ out)
{
    int cnt = ((const int*)acc)[2];
    float conf = acc[0] / (float)cnt;                  // ref divides by n_pos (no clamp)
    float loc  = acc[1] / fmaxf((float)cnt, 1.f);      // ref clamps denominator to 1
    out[0] = conf + loc;
}

extern "C" void kernel_launch(void* const* d_in, const int* in_sizes, int n_in,
                              void* d_out, int out_size, void* d_ws, size_t ws_size,
                              hipStream_t stream)
{
    const float* locs   = (const float*)d_in[0];   // (32, 8525, 4)
    const float* scores = (const float*)d_in[1];   // (32, 8525, 80)
    const float* boxes  = (const float*)d_in[2];   // (32, 16, 4)
    const int*   labels = (const int*)d_in[3];     // (32, 16)
    const float* priors = (const float*)d_in[4];   // (8525, 4)
    float* out = (float*)d_out;
    float* acc = (float*)d_ws;

    hipMemsetAsync(acc, 0, 16, stream);
    atss_main<<<TOTAL_BLOCKS, 256, 0, stream>>>(locs, scores, boxes, labels, priors, acc);
    atss_finalize<<<1, 1, 0, stream>>>(acc, out);
}

// Round 2
// 190.399 us; speedup vs baseline: 2.7094x; 2.7094x over previous
//
#include <hip/hip_runtime.h>
#include <math.h>

#define KGT   16
#define NCAND 9
#define NLVL  5
#define NPRI  8525
#define NCLS  80
#define NIMG  32

#define SCAN_TASKS  (NIMG * KGT * NLVL)   // 2560 (one wave each)
#define SCAN_BLOCKS (SCAN_TASKS / 4)      // 640 blocks of 4 waves
#define FOCAL_BLOCKS 2016
#define TOTAL_BLOCKS (SCAN_BLOCKS + FOCAL_BLOCKS)

__constant__ int d_SPL[6] = {0, 6400, 8000, 8400, 8500, 8525};

// ws layout: [0..3]   float acc: acc[0]=focal sum, acc[1]=loc sum, ((int*)acc)[2]=count
//            [64..]   float povs[2560*9]   (23040 floats)
//            [next]   int   idxs[2560*9]

// ---------------------------------------------------------------- kernel 1
// blocks [0, SCAN_BLOCKS): one wave per (image,gt,level) top-9 scan + IoU
// blocks [SCAN_BLOCKS, TOTAL): grid-stride focal base sum over all logits
__global__ __launch_bounds__(256)
void atss_scan_focal(const float* __restrict__ scores,
                     const float* __restrict__ boxes,
                     const float* __restrict__ priors,
                     float* __restrict__ acc,
                     float* __restrict__ povs,
                     int*   __restrict__ idxs)
{
    const int tid = threadIdx.x;
    const int blk = blockIdx.x;
    __shared__ float wsum[4];

    if (blk >= SCAN_BLOCKS) {
        // focal base: sum 0.75 * p^2 * softplus(x) over every logit
        const int n4 = (NIMG * NPRI * NCLS) / 4;
        const float4* s4 = (const float4*)scores;
        int gid = (blk - SCAN_BLOCKS) * 256 + tid;
        const int stride = FOCAL_BLOCKS * 256;
        float lsum = 0.f;
        for (int i = gid; i < n4; i += stride) {
            float4 v = s4[i];
            #pragma unroll
            for (int c = 0; c < 4; ++c) {
                float x = (c == 0) ? v.x : (c == 1) ? v.y : (c == 2) ? v.z : v.w;
                float e  = __expf(-fabsf(x));
                float sp = fmaxf(x, 0.f) + __logf(1.f + e);           // softplus(x)
                float p  = (x >= 0.f) ? 1.f / (1.f + e) : e / (1.f + e); // sigmoid
                lsum += p * p * sp;
            }
        }
        #pragma unroll
        for (int off = 32; off > 0; off >>= 1) lsum += __shfl_down(lsum, off);
        if ((tid & 63) == 0) wsum[tid >> 6] = lsum;
        __syncthreads();
        if (tid == 0)
            atomicAdd(&acc[0], 0.75f * (wsum[0] + wsum[1] + wsum[2] + wsum[3]));
        return;
    }

    // ---------------- scan: one wave per task t = (b, g, l)
    const int lane = tid & 63;
    const int t = blk * 4 + (tid >> 6);          // [0, 2560)
    const int b = t / (KGT * NLVL);
    const int r = t % (KGT * NLVL);
    const int g = r / NLVL;
    const int l = r % NLVL;

    const int SPLc[6] = {0, 6400, 8000, 8400, 8500, 8525};
    const int base = SPLc[l];
    const int Pl   = SPLc[l + 1] - base;

    float4 bx = ((const float4*)boxes)[b * KGT + g];
    const float gcx = (bx.x + bx.z) * 0.5f;
    const float gcy = (bx.y + bx.w) * 0.5f;

    // per-lane sorted top-9 of packed (dist_bits, idx)
    unsigned long long L[NCAND];
    #pragma unroll
    for (int s = 0; s < NCAND; ++s) L[s] = ~0ull;

    for (int i = lane; i < Pl; i += 64) {
        float2 pc = ((const float2*)priors)[(base + i) * 2];
        float dx = gcx - pc.x, dy = gcy - pc.y;
        float dist = sqrtf(dx * dx + dy * dy);
        unsigned long long pk =
            ((unsigned long long)__float_as_uint(dist) << 32) | (unsigned)i;
        if (pk < L[NCAND - 1]) {
            L[NCAND - 1] = pk;
            #pragma unroll
            for (int s = NCAND - 1; s >= 1; --s) {
                if (L[s] < L[s - 1]) {
                    unsigned long long tw = L[s]; L[s] = L[s - 1]; L[s - 1] = tw;
                } else break;
            }
        }
    }

    // 9 rounds of wave-wide min extraction (all packed values are unique)
    unsigned long long mine = 0;
    #pragma unroll
    for (int rnd = 0; rnd < NCAND; ++rnd) {
        unsigned long long m = L[0];
        #pragma unroll
        for (int off = 1; off < 64; off <<= 1) {
            unsigned long long o = __shfl_xor(m, off);
            m = (o < m) ? o : m;
        }
        if (L[0] == m) {          // unique winner pops its head
            #pragma unroll
            for (int s = 0; s < NCAND - 1; ++s) L[s] = L[s + 1];
            L[NCAND - 1] = ~0ull;
        }
        if (lane == rnd) mine = m;
    }

    if (lane < NCAND) {
        int idx = (int)(unsigned)(mine & 0xffffffffull);
        float4 pr = ((const float4*)priors)[base + idx];
        float px0 = pr.x - pr.z * 0.5f, py0 = pr.y - pr.w * 0.5f;
        float px1 = pr.x + pr.z * 0.5f, py1 = pr.y + pr.w * 0.5f;
        float iw = fmaxf(fminf(bx.z, px1) - fmaxf(bx.x, px0), 0.f);
        float ih = fmaxf(fminf(bx.w, py1) - fmaxf(bx.y, py0), 0.f);
        float inter = iw * ih;
        float areaA = (bx.z - bx.x) * (bx.w - bx.y);
        float areaP = (px1 - px0) * (py1 - py0);
        float iou = inter / (areaA + areaP - inter);
        int o = t * NCAND + lane;       // layout: ((b*16+g)*5 + l)*9 + j
        povs[o] = iou;
        idxs[o] = idx;
    }
}

// ---------------------------------------------------------------- kernel 2
// per-image: adaptive threshold, argmax-over-GT, focal correction + CIoU
__global__ __launch_bounds__(256)
void atss_decide(const float* __restrict__ locs,
                 const float* __restrict__ scores,
                 const float* __restrict__ boxes,
                 const int*   __restrict__ labels,
                 const float* __restrict__ priors,
                 const float* __restrict__ povs,
                 const int*   __restrict__ idxs,
                 float* __restrict__ acc)
{
    const int tid = threadIdx.x;
    const int b = blockIdx.x;
    const int SPLc[6] = {0, 6400, 8000, 8400, 8500, 8525};

    __shared__ float pov[KGT * 45];
    __shared__ int   tix[KGT * 45];
    __shared__ float sbox[KGT][4];
    __shared__ int   slab[KGT];
    __shared__ float thr[KGT];

    for (int e = tid; e < KGT * 45; e += 256) {
        pov[e] = povs[b * (KGT * 45) + e];
        tix[e] = idxs[b * (KGT * 45) + e];
    }
    if (tid < KGT) {
        float4 bxv = ((const float4*)boxes)[b * KGT + tid];
        sbox[tid][0] = bxv.x; sbox[tid][1] = bxv.y;
        sbox[tid][2] = bxv.z; sbox[tid][3] = bxv.w;
        slab[tid] = labels[b * KGT + tid];
    }
    __syncthreads();

    if (tid < KGT) {
        float s = 0.f;
        for (int q = 0; q < 45; ++q) s += pov[tid * 45 + q];
        float mean = s / 45.f;
        float ss = 0.f;
        for (int q = 0; q < 45; ++q) { float d = pov[tid * 45 + q] - mean; ss += d * d; }
        thr[tid] = mean + sqrtf(ss / 44.f);
    }
    __syncthreads();

    if (tid < NLVL * NCAND) {
        int l = tid / NCAND, j = tid % NCAND;
        float bestv = -1.f; int bestg = 0;
        #pragma unroll
        for (int gg = 0; gg < KGT; ++gg) {
            float m = pov[gg * 45 + tid];
            int pi = tix[gg * 45 + tid];
            float4 pr = ((const float4*)priors)[SPLc[l] + pi];
            bool inside = (sbox[gg][0] < pr.x) && (pr.x < sbox[gg][2]) &&
                          (sbox[gg][1] < pr.y) && (pr.y < sbox[gg][3]);
            float mm = ((m > thr[gg]) && inside) ? m : 0.f;
            if (mm > bestv) { bestv = mm; bestg = gg; }   // first max wins
        }
        if (bestv > 0.f) {
            int lab = slab[bestg];
            // focal correction at prior SPL[l]+j, class lab (ref's .at[arange(9)] quirk)
            long pos = (long)b * NPRI + SPLc[l] + j;
            float x  = scores[pos * NCLS + (lab - 1)];
            float e  = expf(-fabsf(x));
            float l1 = log1pf(e);
            float spp = fmaxf(x, 0.f) + l1;
            float spn = fmaxf(-x, 0.f) + l1;
            float p   = (x >= 0.f) ? 1.f / (1.f + e) : e / (1.f + e);
            float corr = 0.25f * (1.f - p) * (1.f - p) * spn - 0.75f * p * p * spp;

            // decode pred box at matched prior, CIoU vs gt
            int pi = tix[bestg * 45 + tid];
            float4 pr = ((const float4*)priors)[SPLc[l] + pi];
            float4 lc = ((const float4*)locs)[b * NPRI + SPLc[l] + pi];
            float cx = lc.x * pr.z / 10.f + pr.x;
            float cy = lc.y * pr.w / 10.f + pr.y;
            float w  = expf(lc.z / 5.f) * pr.z;
            float h  = expf(lc.w / 5.f) * pr.w;
            float qx0 = cx - w * 0.5f, qy0 = cy - h * 0.5f;
            float qx1 = cx + w * 0.5f, qy1 = cy + h * 0.5f;
            float gx0 = sbox[bestg][0], gy0 = sbox[bestg][1];
            float gx1 = sbox[bestg][2], gy1 = sbox[bestg][3];
            float w1 = qx1 - qx0, h1 = qy1 - qy0, w2 = gx1 - gx0, h2 = gy1 - gy0;
            float iw = fmaxf(fminf(qx1, gx1) - fmaxf(qx0, gx0), 0.f);
            float ih = fmaxf(fminf(qy1, gy1) - fmaxf(qy0, gy0), 0.f);
            float inter = iw * ih;
            float iou = inter / (w1 * h1 + w2 * h2 - inter);
            float dcx = (qx0 + qx1) * 0.5f - (gx0 + gx1) * 0.5f;
            float dcy = (qy0 + qy1) * 0.5f - (gy0 + gy1) * 0.5f;
            float rho2 = dcx * dcx + dcy * dcy;
            float ex = fmaxf(qx1, gx1) - fminf(qx0, gx0);
            float ey = fmaxf(qy1, gy1) - fminf(qy0, gy0);
            float cdiag = ex * ex + ey * ey;
            float da = atanf(w2 / h2) - atanf(w1 / h1);
            float v  = 0.4052847345693511f * da * da;     // 4/pi^2
            float alpha = v / (1.f - iou + v);
            float ci = iou - rho2 / cdiag - alpha * v;
            ci = fminf(fmaxf(ci, -1.f), 1.f);

            atomicAdd(&acc[0], corr);
            atomicAdd(&acc[1], 1.f - ci);
            atomicAdd((int*)acc + 2, 1);
        }
    }
}

__global__ void atss_finalize(const float* __restrict__ acc, float* __restrict__ out)
{
    int cnt = ((const int*)acc)[2];
    float conf = acc[0] / (float)cnt;               // ref: / n_pos (no clamp)
    float loc  = acc[1] / fmaxf((float)cnt, 1.f);   // ref: clamped denom
    out[0] = conf + loc;
}

extern "C" void kernel_launch(void* const* d_in, const int* in_sizes, int n_in,
                              void* d_out, int out_size, void* d_ws, size_t ws_size,
                              hipStream_t stream)
{
    const float* locs   = (const float*)d_in[0];   // (32, 8525, 4)
    const float* scores = (const float*)d_in[1];   // (32, 8525, 80)
    const float* boxes  = (const float*)d_in[2];   // (32, 16, 4)
    const int*   labels = (const int*)d_in[3];     // (32, 16)
    const float* priors = (const float*)d_in[4];   // (8525, 4)
    float* out = (float*)d_out;

    float* acc  = (float*)d_ws;
    float* povs = (float*)((char*)d_ws + 64);
    int*   idxs = (int*)((char*)d_ws + 64 + SCAN_TASKS * NCAND * sizeof(float));

    hipMemsetAsync(acc, 0, 16, stream);
    atss_scan_focal<<<TOTAL_BLOCKS, 256, 0, stream>>>(scores, boxes, priors,
                                                      acc, povs, idxs);
    atss_decide<<<NIMG, 256, 0, stream>>>(locs, scores, boxes, labels, priors,
                                          povs, idxs, acc);
    atss_finalize<<<1, 1, 0, stream>>>(acc, out);
}